// Round 1
// baseline (1524.405 us; speedup 1.0000x reference)
//
#include <hip/hip_runtime.h>
#include <hip/hip_bf16.h>

#define IN_CH 256
#define OUT_CH 128
#define NODE_TILE 8

// h = x @ W.T + b    x:[N,256] W:[128,256] b:[128] -> h:[N,128]
__global__ void __launch_bounds__(128) linear_kernel(
    const float* __restrict__ x, const float* __restrict__ W,
    const float* __restrict__ b, float* __restrict__ h, int n_nodes) {
    __shared__ float xs[NODE_TILE][IN_CH];
    const int tid = threadIdx.x;              // 0..127
    const int node0 = blockIdx.x * NODE_TILE;

    // stage NODE_TILE x-rows into LDS: 8*256 floats = 512 float4, 128 threads -> 4 each
    for (int i = tid; i < NODE_TILE * IN_CH / 4; i += 128) {
        int m = (i * 4) / IN_CH;
        int k = (i * 4) % IN_CH;
        int node = node0 + m;
        float4 v = make_float4(0.f, 0.f, 0.f, 0.f);
        if (node < n_nodes)
            v = *reinterpret_cast<const float4*>(x + (size_t)node * IN_CH + k);
        *reinterpret_cast<float4*>(&xs[m][k]) = v;
    }
    __syncthreads();

    float acc[NODE_TILE];
    const float bias = b[tid];
#pragma unroll
    for (int m = 0; m < NODE_TILE; ++m) acc[m] = bias;

    const float* wrow = W + (size_t)tid * IN_CH;
#pragma unroll 4
    for (int k = 0; k < IN_CH; k += 4) {
        float4 wv = *reinterpret_cast<const float4*>(wrow + k);
#pragma unroll
        for (int m = 0; m < NODE_TILE; ++m) {
            acc[m] += xs[m][k] * wv.x + xs[m][k + 1] * wv.y +
                      xs[m][k + 2] * wv.z + xs[m][k + 3] * wv.w;
        }
    }

#pragma unroll
    for (int m = 0; m < NODE_TILE; ++m) {
        int node = node0 + m;
        if (node < n_nodes) h[(size_t)node * OUT_CH + tid] = acc[m];
    }
}

// out[dst[e]] += w[e] * h[src[e]]   — one wave per edge, 2 channels (float2) per lane
__global__ void __launch_bounds__(256) scatter_kernel(
    const float* __restrict__ h, const int* __restrict__ edge_src,
    const int* __restrict__ edge_dst, const float* __restrict__ edge_weight,
    float* __restrict__ out, long long n_edges) {
    const long long nthreads = (long long)gridDim.x * blockDim.x;
    const long long total = n_edges * 64;  // 64 lanes per edge
    for (long long idx = (long long)blockIdx.x * blockDim.x + threadIdx.x;
         idx < total; idx += nthreads) {
        const long long e = idx >> 6;       // wave-uniform (threads are wave-consecutive)
        const int lane = (int)(idx & 63);   // channel pair index
        const int s = edge_src[e];
        const int d = edge_dst[e];
        const float w = edge_weight[e];
        const float2 hv = *reinterpret_cast<const float2*>(h + (size_t)s * OUT_CH + 2 * lane);
        float* op = out + (size_t)d * OUT_CH + 2 * lane;
        unsafeAtomicAdd(op + 0, w * hv.x);
        unsafeAtomicAdd(op + 1, w * hv.y);
    }
}

extern "C" void kernel_launch(void* const* d_in, const int* in_sizes, int n_in,
                              void* d_out, int out_size, void* d_ws, size_t ws_size,
                              hipStream_t stream) {
    const float* x           = (const float*)d_in[0];
    const int*   edge_src    = (const int*)d_in[1];
    const int*   edge_dst    = (const int*)d_in[2];
    const float* edge_weight = (const float*)d_in[3];
    const float* W           = (const float*)d_in[4];
    const float* b           = (const float*)d_in[5];
    float* out = (float*)d_out;

    const int n_nodes = in_sizes[0] / IN_CH;
    const long long n_edges = in_sizes[1];

    float* h = (float*)d_ws;  // n_nodes * OUT_CH floats = 51.2 MB

    // zero the output accumulator
    hipMemsetAsync(out, 0, (size_t)out_size * sizeof(float), stream);

    // 1) projection
    int gblocks = (n_nodes + NODE_TILE - 1) / NODE_TILE;
    linear_kernel<<<gblocks, 128, 0, stream>>>(x, W, b, h, n_nodes);

    // 2) scatter-add
    scatter_kernel<<<2048, 256, 0, stream>>>(h, edge_src, edge_dst, edge_weight,
                                             out, n_edges);
}

// Round 2
// 520.759 us; speedup vs baseline: 2.9273x; 2.9273x over previous
//
#include <hip/hip_runtime.h>
#include <hip/hip_bf16.h>

#define IN_CH 256
#define OUT_CH 128
#define NODE_TILE 8
#define CHUNK 1024

// ---------------- 1) h = x @ W.T + b ----------------
__global__ void __launch_bounds__(128) linear_kernel(
    const float* __restrict__ x, const float* __restrict__ W,
    const float* __restrict__ b, float* __restrict__ h, int n_nodes) {
    __shared__ float xs[NODE_TILE][IN_CH];
    const int tid = threadIdx.x;
    const int node0 = blockIdx.x * NODE_TILE;

    for (int i = tid; i < NODE_TILE * IN_CH / 4; i += 128) {
        int m = (i * 4) / IN_CH;
        int k = (i * 4) % IN_CH;
        int node = node0 + m;
        float4 v = make_float4(0.f, 0.f, 0.f, 0.f);
        if (node < n_nodes)
            v = *reinterpret_cast<const float4*>(x + (size_t)node * IN_CH + k);
        *reinterpret_cast<float4*>(&xs[m][k]) = v;
    }
    __syncthreads();

    float acc[NODE_TILE];
    const float bias = b[tid];
#pragma unroll
    for (int m = 0; m < NODE_TILE; ++m) acc[m] = bias;

    const float* wrow = W + (size_t)tid * IN_CH;
#pragma unroll 4
    for (int k = 0; k < IN_CH; k += 4) {
        float4 wv = *reinterpret_cast<const float4*>(wrow + k);
#pragma unroll
        for (int m = 0; m < NODE_TILE; ++m) {
            acc[m] += xs[m][k] * wv.x + xs[m][k + 1] * wv.y +
                      xs[m][k + 2] * wv.z + xs[m][k + 3] * wv.w;
        }
    }
#pragma unroll
    for (int m = 0; m < NODE_TILE; ++m) {
        int node = node0 + m;
        if (node < n_nodes) h[(size_t)node * OUT_CH + tid] = acc[m];
    }
}

// ---------------- 2) histogram of dst ----------------
__global__ void __launch_bounds__(256) hist_kernel(
    const int* __restrict__ edge_dst, int* __restrict__ counts, int n_edges) {
    int e = blockIdx.x * 256 + threadIdx.x;
    if (e < n_edges) atomicAdd(&counts[edge_dst[e]], 1);
}

// ---------------- 3) hierarchical exclusive scan ----------------
__global__ void __launch_bounds__(256) scan_chunk_sums(
    const int* __restrict__ counts, int* __restrict__ partials, int n) {
    __shared__ int sdata[256];
    const int base = blockIdx.x * CHUNK;
    int sum = 0;
    for (int i = threadIdx.x; i < CHUNK; i += 256) {
        int idx = base + i;
        sum += (idx < n) ? counts[idx] : 0;
    }
    sdata[threadIdx.x] = sum;
    __syncthreads();
    for (int s = 128; s > 0; s >>= 1) {
        if (threadIdx.x < s) sdata[threadIdx.x] += sdata[threadIdx.x + s];
        __syncthreads();
    }
    if (threadIdx.x == 0) partials[blockIdx.x] = sdata[0];
}

__global__ void __launch_bounds__(128) scan_partials_kernel(int* partials, int nchunk) {
    __shared__ int sp[256];
    int tid = threadIdx.x;
    for (int i = tid; i < nchunk; i += 128) sp[i] = partials[i];
    __syncthreads();
    if (tid == 0) {
        int run = 0;
        for (int c = 0; c < nchunk; ++c) { int t = sp[c]; sp[c] = run; run += t; }
    }
    __syncthreads();
    for (int i = tid; i < nchunk; i += 128) partials[i] = sp[i];
}

// counts (in cursor) -> exclusive scan; writes offsets[] and cursor[] (write pointers)
__global__ void __launch_bounds__(256) scan_within_kernel(
    int* __restrict__ cursor, int* __restrict__ offsets,
    const int* __restrict__ partials, int n) {
    __shared__ int tsum[256];
    const int tid = threadIdx.x;
    const int i0 = blockIdx.x * CHUNK + tid * 4;
    int vals[4];
    int loc = 0;
#pragma unroll
    for (int j = 0; j < 4; ++j) {
        int idx = i0 + j;
        vals[j] = (idx < n) ? cursor[idx] : 0;
        loc += vals[j];
    }
    tsum[tid] = loc;
    __syncthreads();
    int inc = loc;
    for (int s = 1; s < 256; s <<= 1) {
        int y = (tid >= s) ? tsum[tid - s] : 0;
        __syncthreads();
        inc += y;
        tsum[tid] = inc;
        __syncthreads();
    }
    int run = partials[blockIdx.x] + (inc - loc);  // exclusive prefix
#pragma unroll
    for (int j = 0; j < 4; ++j) {
        int idx = i0 + j;
        if (idx < n) { offsets[idx] = run; cursor[idx] = run; }
        run += vals[j];
    }
}

// ---------------- 4) scatter edges into dst-sorted order ----------------
__global__ void __launch_bounds__(256) scatter_sort_kernel(
    const int* __restrict__ edge_src, const int* __restrict__ edge_dst,
    const float* __restrict__ edge_weight, int* __restrict__ cursor,
    int* __restrict__ sorted_src, float* __restrict__ sorted_w, int n_edges) {
    int e = blockIdx.x * 256 + threadIdx.x;
    if (e < n_edges) {
        int d = edge_dst[e];
        int pos = atomicAdd(&cursor[d], 1);
        sorted_src[pos] = edge_src[e];
        sorted_w[pos] = edge_weight[e];
    }
}

// ---------------- 5) per-node segmented reduction: one wave per dst ----------------
__global__ void __launch_bounds__(256) agg_kernel(
    const float* __restrict__ h, const int* __restrict__ offsets,
    const int* __restrict__ sorted_src, const float* __restrict__ sorted_w,
    float* __restrict__ out, int n_nodes, int n_edges) {
    const int wave = (blockIdx.x * 256 + threadIdx.x) >> 6;
    const int lane = threadIdx.x & 63;
    if (wave >= n_nodes) return;
    const int start = offsets[wave];
    const int end = (wave == n_nodes - 1) ? n_edges : offsets[wave + 1];
    float2 acc = make_float2(0.f, 0.f);
    int i = start;
    for (; i + 1 < end; i += 2) {
        int s0 = sorted_src[i], s1 = sorted_src[i + 1];
        float w0 = sorted_w[i], w1 = sorted_w[i + 1];
        const float2 a = *reinterpret_cast<const float2*>(h + (size_t)s0 * OUT_CH + 2 * lane);
        const float2 c = *reinterpret_cast<const float2*>(h + (size_t)s1 * OUT_CH + 2 * lane);
        acc.x += w0 * a.x + w1 * c.x;
        acc.y += w0 * a.y + w1 * c.y;
    }
    if (i < end) {
        int s0 = sorted_src[i];
        float w0 = sorted_w[i];
        const float2 a = *reinterpret_cast<const float2*>(h + (size_t)s0 * OUT_CH + 2 * lane);
        acc.x += w0 * a.x;
        acc.y += w0 * a.y;
    }
    *reinterpret_cast<float2*>(out + (size_t)wave * OUT_CH + 2 * lane) = acc;
}

extern "C" void kernel_launch(void* const* d_in, const int* in_sizes, int n_in,
                              void* d_out, int out_size, void* d_ws, size_t ws_size,
                              hipStream_t stream) {
    const float* x           = (const float*)d_in[0];
    const int*   edge_src    = (const int*)d_in[1];
    const int*   edge_dst    = (const int*)d_in[2];
    const float* edge_weight = (const float*)d_in[3];
    const float* W           = (const float*)d_in[4];
    const float* b           = (const float*)d_in[5];
    float* out = (float*)d_out;

    const int n_nodes = in_sizes[0] / IN_CH;
    const int n_edges = in_sizes[1];
    const int nchunk = (n_nodes + CHUNK - 1) / CHUNK;

    // workspace layout
    float* h          = (float*)d_ws;                       // n_nodes*128 floats
    int*   offsets    = (int*)(h + (size_t)n_nodes * OUT_CH);
    int*   cursor     = offsets + n_nodes;
    int*   partials   = cursor + n_nodes;
    int*   sorted_src = partials + 256;
    float* sorted_w   = (float*)(sorted_src + n_edges);

    hipMemsetAsync(cursor, 0, (size_t)n_nodes * sizeof(int), stream);

    // 1) projection
    linear_kernel<<<(n_nodes + NODE_TILE - 1) / NODE_TILE, 128, 0, stream>>>(
        x, W, b, h, n_nodes);

    // 2-4) build dst-CSR
    const int eblocks = (n_edges + 255) / 256;
    hist_kernel<<<eblocks, 256, 0, stream>>>(edge_dst, cursor, n_edges);
    scan_chunk_sums<<<nchunk, 256, 0, stream>>>(cursor, partials, n_nodes);
    scan_partials_kernel<<<1, 128, 0, stream>>>(partials, nchunk);
    scan_within_kernel<<<nchunk, 256, 0, stream>>>(cursor, offsets, partials, n_nodes);
    scatter_sort_kernel<<<eblocks, 256, 0, stream>>>(
        edge_src, edge_dst, edge_weight, cursor, sorted_src, sorted_w, n_edges);

    // 5) segmented reduction (writes every out element; no memset of out needed)
    const int ablocks = (n_nodes * 64 + 255) / 256;
    agg_kernel<<<ablocks, 256, 0, stream>>>(
        h, offsets, sorted_src, sorted_w, out, n_nodes, n_edges);
}

// Round 3
// 321.299 us; speedup vs baseline: 4.7445x; 1.6208x over previous
//
#include <hip/hip_runtime.h>
#include <hip/hip_bf16.h>

#define IN_CH 256
#define OUT_CH 128
#define CHUNK 1024

using bf16x8 = __attribute__((ext_vector_type(8))) __bf16;
using f32x16 = __attribute__((ext_vector_type(16))) float;

__device__ __forceinline__ unsigned int f2bf(float f) {
    union { float f; unsigned u; } v; v.f = f;
    unsigned r = v.u + 0x7fffu + ((v.u >> 16) & 1u);
    return r >> 16;  // RNE bf16 bits in low 16
}
__device__ __forceinline__ float bf2f(unsigned short u) {
    union { unsigned u; float f; } v; v.u = ((unsigned)u) << 16;
    return v.f;
}

// ---------------- 0) pack W (f32 [128][256]) into MFMA B-fragment order ----------------
// frag flat = (c*16 + ks)*64 + lane ; elements i=0..7 : W[32c + (lane&31)][16ks + 8*(lane>>5) + i]
__global__ void __launch_bounds__(256) prep_w(const float* __restrict__ W,
                                              unsigned short* __restrict__ Wfrag) {
    const int flat = blockIdx.x * 256 + threadIdx.x;  // 0..4095
    const int l = flat & 63;
    const int ks = (flat >> 6) & 15;
    const int c = flat >> 10;
    const int row = c * 32 + (l & 31);
    const int col0 = ks * 16 + 8 * (l >> 5);
    const float* src = W + (size_t)row * IN_CH + col0;
    uint4 o;
    o.x = f2bf(src[0]) | (f2bf(src[1]) << 16);
    o.y = f2bf(src[2]) | (f2bf(src[3]) << 16);
    o.z = f2bf(src[4]) | (f2bf(src[5]) << 16);
    o.w = f2bf(src[6]) | (f2bf(src[7]) << 16);
    *reinterpret_cast<uint4*>(Wfrag + (size_t)flat * 8) = o;
}

// ---------------- 1) h = bf16(x @ W.T + b) via 32x32x16 bf16 MFMA ----------------
// block = 4 waves; wave w owns rows [node0 + 32w, +32), all 128 cols (4 col-tiles)
__global__ void __launch_bounds__(256) linear_mfma(
    const float* __restrict__ x, const unsigned short* __restrict__ Wfrag,
    const float* __restrict__ b, unsigned short* __restrict__ h, int n_nodes) {
    const int tid = threadIdx.x;
    const int w = tid >> 6, l = tid & 63;
    const int l31 = l & 31, lh = l >> 5;
    const int node0 = blockIdx.x * 128 + w * 32;

    int arow = node0 + l31;
    if (arow > n_nodes - 1) arow = n_nodes - 1;
    const float* xrow = x + (size_t)arow * IN_CH + 8 * lh;
    const uint4* wf = reinterpret_cast<const uint4*>(Wfrag);

    f32x16 acc0 = {}, acc1 = {}, acc2 = {}, acc3 = {};

#pragma unroll 4
    for (int ks = 0; ks < 16; ++ks) {
        float4 a0 = *reinterpret_cast<const float4*>(xrow + ks * 16);
        float4 a1 = *reinterpret_cast<const float4*>(xrow + ks * 16 + 4);
        uint4 ap;
        ap.x = f2bf(a0.x) | (f2bf(a0.y) << 16);
        ap.y = f2bf(a0.z) | (f2bf(a0.w) << 16);
        ap.z = f2bf(a1.x) | (f2bf(a1.y) << 16);
        ap.w = f2bf(a1.z) | (f2bf(a1.w) << 16);
        bf16x8 af = __builtin_bit_cast(bf16x8, ap);

        uint4 bw0 = wf[(0 * 16 + ks) * 64 + l];
        uint4 bw1 = wf[(1 * 16 + ks) * 64 + l];
        uint4 bw2 = wf[(2 * 16 + ks) * 64 + l];
        uint4 bw3 = wf[(3 * 16 + ks) * 64 + l];

        acc0 = __builtin_amdgcn_mfma_f32_32x32x16_bf16(af, __builtin_bit_cast(bf16x8, bw0), acc0, 0, 0, 0);
        acc1 = __builtin_amdgcn_mfma_f32_32x32x16_bf16(af, __builtin_bit_cast(bf16x8, bw1), acc1, 0, 0, 0);
        acc2 = __builtin_amdgcn_mfma_f32_32x32x16_bf16(af, __builtin_bit_cast(bf16x8, bw2), acc2, 0, 0, 0);
        acc3 = __builtin_amdgcn_mfma_f32_32x32x16_bf16(af, __builtin_bit_cast(bf16x8, bw3), acc3, 0, 0, 0);
    }

    const float bias0 = b[0 + l31], bias1 = b[32 + l31], bias2 = b[64 + l31], bias3 = b[96 + l31];
#pragma unroll
    for (int reg = 0; reg < 16; ++reg) {
        const int r = (reg & 3) + 8 * (reg >> 2) + 4 * lh;  // D: row=(reg&3)+8*(reg>>2)+4*(lane>>5)
        const int node = node0 + r;
        if (node < n_nodes) {
            unsigned short* hp = h + (size_t)node * OUT_CH;
            hp[0 + l31]  = (unsigned short)f2bf(acc0[reg] + bias0);
            hp[32 + l31] = (unsigned short)f2bf(acc1[reg] + bias1);
            hp[64 + l31] = (unsigned short)f2bf(acc2[reg] + bias2);
            hp[96 + l31] = (unsigned short)f2bf(acc3[reg] + bias3);
        }
    }
}

// ---------------- 2) histogram of dst ----------------
__global__ void __launch_bounds__(256) hist_kernel(
    const int* __restrict__ edge_dst, int* __restrict__ counts, int n_edges) {
    int e = blockIdx.x * 256 + threadIdx.x;
    if (e < n_edges) atomicAdd(&counts[edge_dst[e]], 1);
}

// ---------------- 3) hierarchical exclusive scan ----------------
__global__ void __launch_bounds__(256) scan_chunk_sums(
    const int* __restrict__ counts, int* __restrict__ partials, int n) {
    __shared__ int sdata[256];
    const int base = blockIdx.x * CHUNK;
    int sum = 0;
    for (int i = threadIdx.x; i < CHUNK; i += 256) {
        int idx = base + i;
        sum += (idx < n) ? counts[idx] : 0;
    }
    sdata[threadIdx.x] = sum;
    __syncthreads();
    for (int s = 128; s > 0; s >>= 1) {
        if (threadIdx.x < s) sdata[threadIdx.x] += sdata[threadIdx.x + s];
        __syncthreads();
    }
    if (threadIdx.x == 0) partials[blockIdx.x] = sdata[0];
}

__global__ void __launch_bounds__(128) scan_partials_kernel(int* partials, int nchunk) {
    __shared__ int sp[256];
    int tid = threadIdx.x;
    for (int i = tid; i < nchunk; i += 128) sp[i] = partials[i];
    __syncthreads();
    if (tid == 0) {
        int run = 0;
        for (int c = 0; c < nchunk; ++c) { int t = sp[c]; sp[c] = run; run += t; }
    }
    __syncthreads();
    for (int i = tid; i < nchunk; i += 128) partials[i] = sp[i];
}

__global__ void __launch_bounds__(256) scan_within_kernel(
    int* __restrict__ cursor, int* __restrict__ offsets,
    const int* __restrict__ partials, int n) {
    __shared__ int tsum[256];
    const int tid = threadIdx.x;
    const int i0 = blockIdx.x * CHUNK + tid * 4;
    int vals[4];
    int loc = 0;
#pragma unroll
    for (int j = 0; j < 4; ++j) {
        int idx = i0 + j;
        vals[j] = (idx < n) ? cursor[idx] : 0;
        loc += vals[j];
    }
    tsum[tid] = loc;
    __syncthreads();
    int inc = loc;
    for (int s = 1; s < 256; s <<= 1) {
        int y = (tid >= s) ? tsum[tid - s] : 0;
        __syncthreads();
        inc += y;
        tsum[tid] = inc;
        __syncthreads();
    }
    int run = partials[blockIdx.x] + (inc - loc);
#pragma unroll
    for (int j = 0; j < 4; ++j) {
        int idx = i0 + j;
        if (idx < n) { offsets[idx] = run; cursor[idx] = run; }
        run += vals[j];
    }
}

// ---------------- 4) scatter edges into dst-sorted order ----------------
__global__ void __launch_bounds__(256) scatter_sort_kernel(
    const int* __restrict__ edge_src, const int* __restrict__ edge_dst,
    const float* __restrict__ edge_weight, int* __restrict__ cursor,
    int* __restrict__ sorted_src, float* __restrict__ sorted_w, int n_edges) {
    int e = blockIdx.x * 256 + threadIdx.x;
    if (e < n_edges) {
        int d = edge_dst[e];
        int pos = atomicAdd(&cursor[d], 1);
        sorted_src[pos] = edge_src[e];
        sorted_w[pos] = edge_weight[e];
    }
}

// ---------------- 5) segmented reduction: one wave per dst, 2 edges in flight ----------------
__global__ void __launch_bounds__(256) agg_kernel(
    const unsigned short* __restrict__ h, const int* __restrict__ offsets,
    const int* __restrict__ sorted_src, const float* __restrict__ sorted_w,
    float* __restrict__ out, int n_nodes, int n_edges) {
    const int wave = (blockIdx.x * 256 + threadIdx.x) >> 6;
    const int lane = threadIdx.x & 63;
    if (wave >= n_nodes) return;
    const int start = offsets[wave];
    const int end = (wave == n_nodes - 1) ? n_edges : offsets[wave + 1];
    const int sub = lane >> 5;          // 2 parallel edge streams per wave
    const int c4 = (lane & 31) * 4;     // 4 channels per lane

    float a0 = 0.f, a1 = 0.f, a2 = 0.f, a3 = 0.f;
    for (int i = start + sub; i < end; i += 2) {
        const int s = sorted_src[i];
        const float w = sorted_w[i];
        const ushort4 hv = *reinterpret_cast<const ushort4*>(h + (size_t)s * OUT_CH + c4);
        a0 += w * bf2f(hv.x);
        a1 += w * bf2f(hv.y);
        a2 += w * bf2f(hv.z);
        a3 += w * bf2f(hv.w);
    }
    a0 += __shfl_xor(a0, 32);
    a1 += __shfl_xor(a1, 32);
    a2 += __shfl_xor(a2, 32);
    a3 += __shfl_xor(a3, 32);
    if (sub == 0) {
        float4 o = make_float4(a0, a1, a2, a3);
        *reinterpret_cast<float4*>(out + (size_t)wave * OUT_CH + c4) = o;
    }
}

extern "C" void kernel_launch(void* const* d_in, const int* in_sizes, int n_in,
                              void* d_out, int out_size, void* d_ws, size_t ws_size,
                              hipStream_t stream) {
    const float* x           = (const float*)d_in[0];
    const int*   edge_src    = (const int*)d_in[1];
    const int*   edge_dst    = (const int*)d_in[2];
    const float* edge_weight = (const float*)d_in[3];
    const float* W           = (const float*)d_in[4];
    const float* b           = (const float*)d_in[5];
    float* out = (float*)d_out;

    const int n_nodes = in_sizes[0] / IN_CH;
    const int n_edges = in_sizes[1];
    const int nchunk = (n_nodes + CHUNK - 1) / CHUNK;

    // workspace layout
    unsigned short* h          = (unsigned short*)d_ws;        // n_nodes*128 bf16
    int*            offsets    = (int*)(h + (size_t)n_nodes * OUT_CH);
    int*            cursor     = offsets + n_nodes;
    int*            partials   = cursor + n_nodes;
    int*            sorted_src = partials + 256;
    float*          sorted_w   = (float*)(sorted_src + n_edges);
    unsigned short* Wfrag      = (unsigned short*)(sorted_w + n_edges);  // 4096*8 bf16 = 64 KB

    hipMemsetAsync(cursor, 0, (size_t)n_nodes * sizeof(int), stream);

    // 0) W -> bf16 fragment order
    prep_w<<<16, 256, 0, stream>>>(W, Wfrag);

    // 1) projection (MFMA)
    linear_mfma<<<(n_nodes + 127) / 128, 256, 0, stream>>>(x, Wfrag, b, h, n_nodes);

    // 2-4) build dst-CSR
    const int eblocks = (n_edges + 255) / 256;
    hist_kernel<<<eblocks, 256, 0, stream>>>(edge_dst, cursor, n_edges);
    scan_chunk_sums<<<nchunk, 256, 0, stream>>>(cursor, partials, n_nodes);
    scan_partials_kernel<<<1, 128, 0, stream>>>(partials, nchunk);
    scan_within_kernel<<<nchunk, 256, 0, stream>>>(cursor, offsets, partials, n_nodes);
    scatter_sort_kernel<<<eblocks, 256, 0, stream>>>(
        edge_src, edge_dst, edge_weight, cursor, sorted_src, sorted_w, n_edges);

    // 5) segmented reduction
    const int ablocks = (n_nodes * 64 + 255) / 256;
    agg_kernel<<<ablocks, 256, 0, stream>>>(
        h, offsets, sorted_src, sorted_w, out, n_nodes, n_edges);
}

// Round 5
// 304.430 us; speedup vs baseline: 5.0074x; 1.0554x over previous
//
#include <hip/hip_runtime.h>
#include <hip/hip_bf16.h>

#define IN_CH 256
#define OUT_CH 128
#define CHUNK 1024

using bf16x8 = __attribute__((ext_vector_type(8))) __bf16;
using f32x16 = __attribute__((ext_vector_type(16))) float;
using f32x4  = __attribute__((ext_vector_type(4))) float;

__device__ __forceinline__ unsigned int f2bf(float f) {
    union { float f; unsigned u; } v; v.f = f;
    unsigned r = v.u + 0x7fffu + ((v.u >> 16) & 1u);
    return r >> 16;
}
__device__ __forceinline__ float bf2f(unsigned short u) {
    union { unsigned u; float f; } v; v.u = ((unsigned)u) << 16;
    return v.f;
}

// ---------------- 0) pack W (f32 [128][256]) into MFMA B-fragment order ----------------
__global__ void __launch_bounds__(256) prep_w(const float* __restrict__ W,
                                              unsigned short* __restrict__ Wfrag) {
    const int flat = blockIdx.x * 256 + threadIdx.x;  // 0..4095
    const int l = flat & 63;
    const int ks = (flat >> 6) & 15;
    const int c = flat >> 10;
    const int row = c * 32 + (l & 31);
    const int col0 = ks * 16 + 8 * (l >> 5);
    const float* src = W + (size_t)row * IN_CH + col0;
    uint4 o;
    o.x = f2bf(src[0]) | (f2bf(src[1]) << 16);
    o.y = f2bf(src[2]) | (f2bf(src[3]) << 16);
    o.z = f2bf(src[4]) | (f2bf(src[5]) << 16);
    o.w = f2bf(src[6]) | (f2bf(src[7]) << 16);
    *reinterpret_cast<uint4*>(Wfrag + (size_t)flat * 8) = o;
}

// ---------------- 1) h = bf16(x @ W.T + b) via 32x32x16 bf16 MFMA ----------------
__global__ void __launch_bounds__(256) linear_mfma(
    const float* __restrict__ x, const unsigned short* __restrict__ Wfrag,
    const float* __restrict__ b, unsigned short* __restrict__ h, int n_nodes) {
    const int tid = threadIdx.x;
    const int w = tid >> 6, l = tid & 63;
    const int l31 = l & 31, lh = l >> 5;
    const int node0 = blockIdx.x * 128 + w * 32;

    int arow = node0 + l31;
    if (arow > n_nodes - 1) arow = n_nodes - 1;
    const float* xrow = x + (size_t)arow * IN_CH + 8 * lh;
    const uint4* wf = reinterpret_cast<const uint4*>(Wfrag);

    f32x16 acc0 = {}, acc1 = {}, acc2 = {}, acc3 = {};

#pragma unroll 4
    for (int ks = 0; ks < 16; ++ks) {
        float4 a0 = *reinterpret_cast<const float4*>(xrow + ks * 16);
        float4 a1 = *reinterpret_cast<const float4*>(xrow + ks * 16 + 4);
        bf16x8 af;
        af[0] = (__bf16)a0.x; af[1] = (__bf16)a0.y;
        af[2] = (__bf16)a0.z; af[3] = (__bf16)a0.w;
        af[4] = (__bf16)a1.x; af[5] = (__bf16)a1.y;
        af[6] = (__bf16)a1.z; af[7] = (__bf16)a1.w;

        uint4 bw0 = wf[(0 * 16 + ks) * 64 + l];
        uint4 bw1 = wf[(1 * 16 + ks) * 64 + l];
        uint4 bw2 = wf[(2 * 16 + ks) * 64 + l];
        uint4 bw3 = wf[(3 * 16 + ks) * 64 + l];

        acc0 = __builtin_amdgcn_mfma_f32_32x32x16_bf16(af, __builtin_bit_cast(bf16x8, bw0), acc0, 0, 0, 0);
        acc1 = __builtin_amdgcn_mfma_f32_32x32x16_bf16(af, __builtin_bit_cast(bf16x8, bw1), acc1, 0, 0, 0);
        acc2 = __builtin_amdgcn_mfma_f32_32x32x16_bf16(af, __builtin_bit_cast(bf16x8, bw2), acc2, 0, 0, 0);
        acc3 = __builtin_amdgcn_mfma_f32_32x32x16_bf16(af, __builtin_bit_cast(bf16x8, bw3), acc3, 0, 0, 0);
    }

    const float bias0 = b[0 + l31], bias1 = b[32 + l31], bias2 = b[64 + l31], bias3 = b[96 + l31];
#pragma unroll
    for (int reg = 0; reg < 16; ++reg) {
        const int r = (reg & 3) + 8 * (reg >> 2) + 4 * lh;
        const int node = node0 + r;
        if (node < n_nodes) {
            unsigned short* hp = h + (size_t)node * OUT_CH;
            __bf16 t0 = (__bf16)(acc0[reg] + bias0);
            __bf16 t1 = (__bf16)(acc1[reg] + bias1);
            __bf16 t2 = (__bf16)(acc2[reg] + bias2);
            __bf16 t3 = (__bf16)(acc3[reg] + bias3);
            hp[0 + l31]  = __builtin_bit_cast(unsigned short, t0);
            hp[32 + l31] = __builtin_bit_cast(unsigned short, t1);
            hp[64 + l31] = __builtin_bit_cast(unsigned short, t2);
            hp[96 + l31] = __builtin_bit_cast(unsigned short, t3);
        }
    }
}

// ---------------- 2) histogram of dst ----------------
__global__ void __launch_bounds__(256) hist_kernel(
    const int* __restrict__ edge_dst, int* __restrict__ counts, int n_edges) {
    int e = blockIdx.x * 256 + threadIdx.x;
    if (e < n_edges) atomicAdd(&counts[edge_dst[e]], 1);
}

// ---------------- 3) hierarchical exclusive scan ----------------
__global__ void __launch_bounds__(256) scan_chunk_sums(
    const int* __restrict__ counts, int* __restrict__ partials, int n) {
    __shared__ int sdata[256];
    const int base = blockIdx.x * CHUNK;
    int sum = 0;
    for (int i = threadIdx.x; i < CHUNK; i += 256) {
        int idx = base + i;
        sum += (idx < n) ? counts[idx] : 0;
    }
    sdata[threadIdx.x] = sum;
    __syncthreads();
    for (int s = 128; s > 0; s >>= 1) {
        if (threadIdx.x < s) sdata[threadIdx.x] += sdata[threadIdx.x + s];
        __syncthreads();
    }
    if (threadIdx.x == 0) partials[blockIdx.x] = sdata[0];
}

__global__ void __launch_bounds__(128) scan_partials_kernel(int* partials, int nchunk) {
    __shared__ int sp[256];
    int tid = threadIdx.x;
    for (int i = tid; i < nchunk; i += 128) sp[i] = partials[i];
    __syncthreads();
    if (tid == 0) {
        int run = 0;
        for (int c = 0; c < nchunk; ++c) { int t = sp[c]; sp[c] = run; run += t; }
    }
    __syncthreads();
    for (int i = tid; i < nchunk; i += 128) partials[i] = sp[i];
}

__global__ void __launch_bounds__(256) scan_within_kernel(
    int* __restrict__ cursor, int* __restrict__ offsets,
    const int* __restrict__ partials, int n) {
    __shared__ int tsum[256];
    const int tid = threadIdx.x;
    const int i0 = blockIdx.x * CHUNK + tid * 4;
    int vals[4];
    int loc = 0;
#pragma unroll
    for (int j = 0; j < 4; ++j) {
        int idx = i0 + j;
        vals[j] = (idx < n) ? cursor[idx] : 0;
        loc += vals[j];
    }
    tsum[tid] = loc;
    __syncthreads();
    int inc = loc;
    for (int s = 1; s < 256; s <<= 1) {
        int y = (tid >= s) ? tsum[tid - s] : 0;
        __syncthreads();
        inc += y;
        tsum[tid] = inc;
        __syncthreads();
    }
    int run = partials[blockIdx.x] + (inc - loc);
#pragma unroll
    for (int j = 0; j < 4; ++j) {
        int idx = i0 + j;
        if (idx < n) { offsets[idx] = run; cursor[idx] = run; }
        run += vals[j];
    }
}

// ---------------- 4) scatter edges: one 8B nontemporal record per edge ----------------
__global__ void __launch_bounds__(256) scatter_sort_kernel(
    const int* __restrict__ edge_src, const int* __restrict__ edge_dst,
    const float* __restrict__ edge_weight, int* __restrict__ cursor,
    unsigned long long* __restrict__ records, int n_edges) {
    int e = blockIdx.x * 256 + threadIdx.x;
    if (e < n_edges) {
        int d = edge_dst[e];
        int pos = atomicAdd(&cursor[d], 1);
        unsigned long long rec =
            ((unsigned long long)__float_as_uint(edge_weight[e]) << 32) |
            (unsigned int)edge_src[e];
        __builtin_nontemporal_store(rec, &records[pos]);
    }
}

// ---------------- 5) segmented reduction: one wave per dst, 4 edge streams ----------------
__global__ void __launch_bounds__(256) agg_kernel(
    const unsigned short* __restrict__ h, const int* __restrict__ offsets,
    const unsigned long long* __restrict__ records,
    float* __restrict__ out, int n_nodes, int n_edges) {
    const int wave = (blockIdx.x * 256 + threadIdx.x) >> 6;
    const int lane = threadIdx.x & 63;
    if (wave >= n_nodes) return;
    const int start = offsets[wave];
    const int end = (wave == n_nodes - 1) ? n_edges : offsets[wave + 1];
    const int sub = lane >> 4;          // 4 parallel edge streams per wave
    const int c8 = (lane & 15) * 8;     // 8 channels per lane

    float a0 = 0.f, a1 = 0.f, a2 = 0.f, a3 = 0.f;
    float a4 = 0.f, a5 = 0.f, a6 = 0.f, a7 = 0.f;
    for (int i = start + sub; i < end; i += 4) {
        const unsigned long long rec = records[i];
        const int s = (int)(rec & 0xffffffffu);
        const float w = __uint_as_float((unsigned int)(rec >> 32));
        const ushort4 hv0 = *reinterpret_cast<const ushort4*>(h + (size_t)s * OUT_CH + c8);
        const ushort4 hv1 = *reinterpret_cast<const ushort4*>(h + (size_t)s * OUT_CH + c8 + 4);
        a0 += w * bf2f(hv0.x); a1 += w * bf2f(hv0.y);
        a2 += w * bf2f(hv0.z); a3 += w * bf2f(hv0.w);
        a4 += w * bf2f(hv1.x); a5 += w * bf2f(hv1.y);
        a6 += w * bf2f(hv1.z); a7 += w * bf2f(hv1.w);
    }
#pragma unroll
    for (int m = 16; m <= 32; m <<= 1) {
        a0 += __shfl_xor(a0, m); a1 += __shfl_xor(a1, m);
        a2 += __shfl_xor(a2, m); a3 += __shfl_xor(a3, m);
        a4 += __shfl_xor(a4, m); a5 += __shfl_xor(a5, m);
        a6 += __shfl_xor(a6, m); a7 += __shfl_xor(a7, m);
    }
    if (lane < 16) {
        float* op = out + (size_t)wave * OUT_CH + c8;
        f32x4 o0 = {a0, a1, a2, a3};
        f32x4 o1 = {a4, a5, a6, a7};
        __builtin_nontemporal_store(o0, reinterpret_cast<f32x4*>(op));
        __builtin_nontemporal_store(o1, reinterpret_cast<f32x4*>(op + 4));
    }
}

extern "C" void kernel_launch(void* const* d_in, const int* in_sizes, int n_in,
                              void* d_out, int out_size, void* d_ws, size_t ws_size,
                              hipStream_t stream) {
    const float* x           = (const float*)d_in[0];
    const int*   edge_src    = (const int*)d_in[1];
    const int*   edge_dst    = (const int*)d_in[2];
    const float* edge_weight = (const float*)d_in[3];
    const float* W           = (const float*)d_in[4];
    const float* b           = (const float*)d_in[5];
    float* out = (float*)d_out;

    const int n_nodes = in_sizes[0] / IN_CH;
    const int n_edges = in_sizes[1];
    const int nchunk = (n_nodes + CHUNK - 1) / CHUNK;

    // workspace layout (8B-aligned blocks first)
    unsigned long long* records = (unsigned long long*)d_ws;            // n_edges * 8B
    unsigned short* h           = (unsigned short*)(records + n_edges); // n_nodes*128 bf16
    int*            offsets     = (int*)(h + (size_t)n_nodes * OUT_CH);
    int*            cursor      = offsets + n_nodes;
    int*            partials    = cursor + n_nodes;
    unsigned short* Wfrag       = (unsigned short*)(partials + 256);    // 64 KB

    hipMemsetAsync(cursor, 0, (size_t)n_nodes * sizeof(int), stream);

    // 0) W -> bf16 fragment order
    prep_w<<<16, 256, 0, stream>>>(W, Wfrag);

    // 1) projection (MFMA)
    linear_mfma<<<(n_nodes + 127) / 128, 256, 0, stream>>>(x, Wfrag, b, h, n_nodes);

    // 2-4) build dst-CSR
    const int eblocks = (n_edges + 255) / 256;
    hist_kernel<<<eblocks, 256, 0, stream>>>(edge_dst, cursor, n_edges);
    scan_chunk_sums<<<nchunk, 256, 0, stream>>>(cursor, partials, n_nodes);
    scan_partials_kernel<<<1, 128, 0, stream>>>(partials, nchunk);
    scan_within_kernel<<<nchunk, 256, 0, stream>>>(cursor, offsets, partials, n_nodes);
    scatter_sort_kernel<<<eblocks, 256, 0, stream>>>(
        edge_src, edge_dst, edge_weight, cursor, records, n_edges);

    // 5) segmented reduction
    const int ablocks = (n_nodes * 64 + 255) / 256;
    agg_kernel<<<ablocks, 256, 0, stream>>>(
        h, offsets, records, out, n_nodes, n_edges);
}